// Round 9
// baseline (231.327 us; speedup 1.0000x reference)
//
#include <hip/hip_runtime.h>

#define TT 200
#define BB 4096

typedef __bf16 bf16x8 __attribute__((ext_vector_type(8)));
typedef float  f32x4  __attribute__((ext_vector_type(4)));

#define L2E 1.4426950408889634f

__device__ __forceinline__ float fexp2(float x) { return __builtin_amdgcn_exp2f(x); }
__device__ __forceinline__ float frcp(float x)  { return __builtin_amdgcn_rcpf(x); }

// Fallback-path init: fill out[T*B] with fc_b[0].
__global__ void gru_init_out(float* __restrict__ out, const float* __restrict__ fc_b) {
    int i = blockIdx.x * blockDim.x + threadIdx.x;
    float v = fc_b[0];
    ((float4*)out)[i] = make_float4(v, v, v, v);
}

// combine: out = out(fwd partial) + ws(bwd partial) + fc_b
__global__ void gru_combine(float* __restrict__ out, const float* __restrict__ ws,
                            const float* __restrict__ fc_b) {
    int i = blockIdx.x * blockDim.x + threadIdx.x;
    float b = fc_b[0];
    float4 a = ((const float4*)out)[i];
    float4 w = ((const float4*)ws)[i];
    ((float4*)out)[i] = make_float4(a.x + w.x + b, a.y + w.y + b,
                                    a.z + w.z + b, a.w + w.w + b);
}

// Register-resident MFMA GRU scan, 4-batch streams: 2048 independent
// single-wave blocks = 2 waves/SIMD, so each SIMD interleaves two serial
// recurrence chains -- the r8 exposed-latency term (~585 cyc/step at 1
// wave/SIMD) hides under the partner wave's issue. Per-wave instruction
// stream is identical to r8 (gate math runs on fixed 4 D-regs/tile; batch
// cols duplicate mod 4, self-consistent).
// A-tiles row-permuted so lane (c0,q)'s D outputs {8q+i / 8q+4+i} are exactly
// its next-step B fragment -> h never leaves registers; no LDS, no barriers.
// Gate weights pre-scaled by -log2e (r,z) / 2log2e (n); sigmoid/tanh =
// rcp(1+exp2(.)) off the MFMA result. fc partial: 16B coalesced plain store.
__global__ __launch_bounds__(64, 2) void gru_scan(
    const float* __restrict__ x,
    const float* __restrict__ w_ih_f, const float* __restrict__ w_hh_f,
    const float* __restrict__ b_ih_f, const float* __restrict__ b_hh_f,
    const float* __restrict__ w_ih_b, const float* __restrict__ w_hh_b,
    const float* __restrict__ b_ih_b, const float* __restrict__ b_hh_b,
    const float* __restrict__ fc_w,
    float* __restrict__ out_f, float* __restrict__ out_b,
    int atomic_mode)
{
    const int tile = blockIdx.x;          // 4-batch tile 0..1023
    const int dir  = blockIdx.y;          // 0 fwd, 1 bwd
    const int lane = threadIdx.x;         // one wave per block
    const int c0   = lane & 15;           // B/D col; A row index m
    const int q    = lane >> 4;           // k-chunk q*8..q*8+7; D rows 4q..4q+3
    const int bl   = c0 & 3;              // effective batch (cols duplicate mod 4)
    const int b0   = tile * 4;

    const float* __restrict__ Wih = dir ? w_ih_b : w_ih_f;
    const float* __restrict__ Whh = dir ? w_hh_b : w_hh_f;
    const float* __restrict__ Bih = dir ? b_ih_b : b_ih_f;
    const float* __restrict__ Bhh = dir ? b_hh_b : b_hh_f;
    float* __restrict__ outp = dir ? out_b : out_f;

    // ---- static fragments, tile idx = 2*gate + s ----
    // A row m=c0 -> weight row 32*gate + 8*(c0>>2) + 4*s + (c0&3)
    // C row  m=4q+i -> weight row 32*gate + 8*q + 4*s + i
    bf16x8 AW[6], AX[6], AFC;
    f32x4  CBrz[4];   // r/z: full bias (bih+bhh) via the x-MFMA C operand
    f32x4  CBxn[2];   // n: bih via x-MFMA C
    f32x4  CBhn[2];   // n: bhh via h-MFMA C
    f32x4  CZ;
    CZ[0] = 0.f; CZ[1] = 0.f; CZ[2] = 0.f; CZ[3] = 0.f;
    #pragma unroll
    for (int gate = 0; gate < 3; ++gate) {
        const float gsc = (gate < 2) ? -L2E : 2.0f * L2E;
        #pragma unroll
        for (int s = 0; s < 2; ++s) {
            const int idx  = 2 * gate + s;
            const int arow = 32 * gate + 8 * (c0 >> 2) + 4 * s + (c0 & 3);
            const float* wrow = Whh + arow * 32 + q * 8;
            #pragma unroll
            for (int j = 0; j < 8; ++j) AW[idx][j] = (__bf16)(gsc * wrow[j]);
            #pragma unroll
            for (int j = 0; j < 8; ++j)
                AX[idx][j] = (q == 0 && j < 3) ? (__bf16)(gsc * Wih[arow * 3 + j])
                                               : (__bf16)0.0f;
            #pragma unroll
            for (int i = 0; i < 4; ++i) {
                const int crow = 32 * gate + 8 * q + 4 * s + i;
                if (gate < 2)  CBrz[idx][i] = gsc * (Bih[crow] + Bhh[crow]);
                else         { CBxn[s][i]   = gsc * Bih[crow];
                               CBhn[s][i]   = gsc * Bhh[crow]; }
            }
        }
    }
    // fc tile: A row 0 = fc_w over all 32 units (natural k order)
    #pragma unroll
    for (int j = 0; j < 8; ++j)
        AFC[j] = (c0 == 0) ? (__bf16)fc_w[dir * 32 + q * 8 + j] : (__bf16)0.0f;

    // ---- h state: fp32 regs; Bh = bf16 B-fragment rebuilt in regs each step ----
    float hA[4] = {0.f, 0.f, 0.f, 0.f};   // units 8q+i,   batch bl
    float hB[4] = {0.f, 0.f, 0.f, 0.f};   // units 8q+4+i, batch bl
    bf16x8 Bh;
    #pragma unroll
    for (int j = 0; j < 8; ++j) Bh[j] = (__bf16)0.0f;

    // x pointer-walk: lane loads x[t][b0+bl][0..2] (cols duplicate mod 4)
    const int  t_first = dir ? (TT - 1) : 0;
    const long xstep   = dir ? -(long)(BB * 3) : (long)(BB * 3);
    const long ostep   = dir ? -(long)BB : (long)BB;
    const float* xp = x + (size_t)t_first * (BB * 3) + (size_t)(b0 + bl) * 3;
    float* ocur = outp + (size_t)t_first * BB + b0;

    float xa = xp[0], xb = xp[1], xc = xp[2];

    for (int t = 0; t < TT; ++t) {
        // x B-fragment: rows k<3 only (AX zero elsewhere)
        bf16x8 Bx;
        Bx[0] = (__bf16)xa; Bx[1] = (__bf16)xb; Bx[2] = (__bf16)xc;
        Bx[3] = (__bf16)0.f; Bx[4] = (__bf16)0.f; Bx[5] = (__bf16)0.f;
        Bx[6] = (__bf16)0.f; Bx[7] = (__bf16)0.f;

        // prefetch next x (no barriers: stays in flight freely)
        const float* xpn = (t < TT - 1) ? (xp + xstep) : xp;
        float nxa = xpn[0], nxb = xpn[1], nxc = xpn[2];
        xp = xpn;

        // r/z: x-MFMA (with full bias in C) chains into h-MFMA C operand
        f32x4 D[6];
        #pragma unroll
        for (int g = 0; g < 4; ++g) {
            f32x4 Dx = __builtin_amdgcn_mfma_f32_16x16x32_bf16(AX[g], Bx, CBrz[g], 0, 0, 0);
            D[g]     = __builtin_amdgcn_mfma_f32_16x16x32_bf16(AW[g], Bh, Dx,      0, 0, 0);
        }
        // n: x and h parts separate (r multiplies only the h part)
        f32x4 Dxn[2];
        #pragma unroll
        for (int s = 0; s < 2; ++s) {
            Dxn[s]   = __builtin_amdgcn_mfma_f32_16x16x32_bf16(AX[4 + s], Bx, CBxn[s], 0, 0, 0);
            D[4 + s] = __builtin_amdgcn_mfma_f32_16x16x32_bf16(AW[4 + s], Bh, CBhn[s], 0, 0, 0);
        }
        // fused FC on h_{t-1} -> out row t-1
        f32x4 Dfc = __builtin_amdgcn_mfma_f32_16x16x32_bf16(AFC, Bh, CZ, 0, 0, 0);
        if (t > 0 && q == 0 && c0 < 4) {
            float* oprev = ocur - ostep + c0;
            if (atomic_mode) atomicAdd(oprev, Dfc[0]);
            else             *oprev = Dfc[0];
        }

        // gates: sigmoid = rcp(1+exp2(s)); tanh = 1-2*rcp(1+exp2(y'))
        #pragma unroll
        for (int i = 0; i < 4; ++i) {
            float rA = frcp(1.0f + fexp2(D[0][i]));
            float rB = frcp(1.0f + fexp2(D[1][i]));
            float zA = frcp(1.0f + fexp2(D[2][i]));
            float zB = frcp(1.0f + fexp2(D[3][i]));
            float eA = fexp2(fmaf(rA, D[4][i], Dxn[0][i]));
            float eB = fexp2(fmaf(rB, D[5][i], Dxn[1][i]));
            float nA = fmaf(-2.0f, frcp(1.0f + eA), 1.0f);
            float nB = fmaf(-2.0f, frcp(1.0f + eB), 1.0f);
            hA[i] = fmaf(zA, hA[i] - nA, nA);
            hB[i] = fmaf(zB, hB[i] - nB, nB);
        }
        // rebuild B fragment in regs: k=q*8+j -> j<4: unit 8q+j (hA), j>=4: hB
        #pragma unroll
        for (int i = 0; i < 4; ++i) {
            Bh[i]     = (__bf16)hA[i];
            Bh[4 + i] = (__bf16)hB[i];
        }

        xa = nxa; xb = nxb; xc = nxc;
        ocur += ostep;
    }

    // epilogue: out row T-1 from the final state
    {
        f32x4 Dfc = __builtin_amdgcn_mfma_f32_16x16x32_bf16(AFC, Bh, CZ, 0, 0, 0);
        if (q == 0 && c0 < 4) {
            float* oprev = ocur - ostep + c0;
            if (atomic_mode) atomicAdd(oprev, Dfc[0]);
            else             *oprev = Dfc[0];
        }
    }
}

extern "C" void kernel_launch(void* const* d_in, const int* in_sizes, int n_in,
                              void* d_out, int out_size, void* d_ws, size_t ws_size,
                              hipStream_t stream) {
    const float* x      = (const float*)d_in[0];
    const float* w_ih_f = (const float*)d_in[1];
    const float* w_hh_f = (const float*)d_in[2];
    const float* b_ih_f = (const float*)d_in[3];
    const float* b_hh_f = (const float*)d_in[4];
    const float* w_ih_b = (const float*)d_in[5];
    const float* w_hh_b = (const float*)d_in[6];
    const float* b_ih_b = (const float*)d_in[7];
    const float* b_hh_b = (const float*)d_in[8];
    const float* fc_w   = (const float*)d_in[9];
    const float* fc_b   = (const float*)d_in[10];
    float* out = (float*)d_out;
    float* ws  = (float*)d_ws;

    const size_t need = (size_t)TT * BB * sizeof(float);
    dim3 grid(BB / 4, 2);   // 1024 tiles x 2 dirs = 2048 single-wave blocks

    if (ws_size >= need) {
        // store path: fwd -> out, bwd -> ws, then combine (adds fc_b)
        gru_scan<<<grid, 64, 0, stream>>>(
            x, w_ih_f, w_hh_f, b_ih_f, b_hh_f,
            w_ih_b, w_hh_b, b_ih_b, b_hh_b, fc_w, out, ws, 0);
        gru_combine<<<(TT * BB / 4) / 256, 256, 0, stream>>>(out, ws, fc_b);
    } else {
        // atomic fallback: init out with fc_b, both dirs accumulate
        gru_init_out<<<(TT * BB / 4 + 255) / 256, 256, 0, stream>>>(out, fc_b);
        gru_scan<<<grid, 64, 0, stream>>>(
            x, w_ih_f, w_hh_f, b_ih_f, b_hh_f,
            w_ih_b, w_hh_b, b_ih_b, b_hh_b, fc_w, out, out, 1);
    }
}

// Round 10
// 161.835 us; speedup vs baseline: 1.4294x; 1.4294x over previous
//
#include <hip/hip_runtime.h>

#define TT 200
#define BB 4096

typedef __bf16 bf16x8 __attribute__((ext_vector_type(8)));
typedef __bf16 bf16x4 __attribute__((ext_vector_type(4)));
typedef float  f32x4  __attribute__((ext_vector_type(4)));
typedef unsigned int u32;
typedef u32 u32x2 __attribute__((ext_vector_type(2)));
typedef u32 u32x4 __attribute__((ext_vector_type(4)));

#define L2E 1.4426950408889634f

__device__ __forceinline__ float fexp2(float x) { return __builtin_amdgcn_exp2f(x); }
__device__ __forceinline__ float frcp(float x)  { return __builtin_amdgcn_rcpf(x); }

// Fallback-path init: fill out[T*B] with fc_b[0].
__global__ void gru_init_out(float* __restrict__ out, const float* __restrict__ fc_b) {
    int i = blockIdx.x * blockDim.x + threadIdx.x;
    float v = fc_b[0];
    ((float4*)out)[i] = make_float4(v, v, v, v);
}

// combine: out = out(fwd partial) + ws(bwd partial) + fc_b
__global__ void gru_combine(float* __restrict__ out, const float* __restrict__ ws,
                            const float* __restrict__ fc_b) {
    int i = blockIdx.x * blockDim.x + threadIdx.x;
    float b = fc_b[0];
    float4 a = ((const float4*)out)[i];
    float4 w = ((const float4*)ws)[i];
    ((float4*)out)[i] = make_float4(a.x + w.x + b, a.y + w.y + b,
                                    a.z + w.z + b, a.w + w.w + b);
}

// Register-resident MFMA GRU scan (r8 base: 8-batch streams, 1024 waves,
// 1 wave/SIMD) with two additions:
//  * trans-split: B/D cols 8-15 duplicate batch 0-7, so lanes c0<8 compute the
//    s=0 unit-half gates and lanes c0>=8 the s=1 half (24 trans ops/lane, half
//    of r8), exchanged via 2x shfl_xor(8) and reassembled into Bh.
//  * deferred fc stores: x8 unrolled chunks buffer fc results in 8 regs and
//    flush once per chunk -> the per-step vmcnt FIFO holds only the x-prefetch
//    (no store-drain in the serial chain). fc-MFMA moved after the Bh rebuild
//    so chunk c yields exactly out rows 8c..8c+7 (no epilogue).
// A-tiles row-permuted so lane (c0,q)'s D outputs are its next-step B fragment:
// h never leaves registers; no LDS, no barriers.
__global__ __launch_bounds__(64, 1) void gru_scan(
    const float* __restrict__ x,
    const float* __restrict__ w_ih_f, const float* __restrict__ w_hh_f,
    const float* __restrict__ b_ih_f, const float* __restrict__ b_hh_f,
    const float* __restrict__ w_ih_b, const float* __restrict__ w_hh_b,
    const float* __restrict__ b_ih_b, const float* __restrict__ b_hh_b,
    const float* __restrict__ fc_w,
    float* __restrict__ out_f, float* __restrict__ out_b,
    int atomic_mode)
{
    const int tile = blockIdx.x;          // 8-batch tile 0..511
    const int dir  = blockIdx.y;          // 0 fwd, 1 bwd
    const int lane = threadIdx.x;         // one wave per block
    const int c0   = lane & 15;           // B/D col; A row index m
    const int q    = lane >> 4;           // k-chunk q*8..q*8+7; D rows 4q..4q+3
    const int bl   = c0 & 7;              // effective batch (cols duplicate mod 8)
    const int b0   = tile * 8;
    const bool lo  = (c0 < 8);            // unit-half owned by this lane

    const float* __restrict__ Wih = dir ? w_ih_b : w_ih_f;
    const float* __restrict__ Whh = dir ? w_hh_b : w_hh_f;
    const float* __restrict__ Bih = dir ? b_ih_b : b_ih_f;
    const float* __restrict__ Bhh = dir ? b_hh_b : b_hh_f;
    float* __restrict__ outp = dir ? out_b : out_f;

    // ---- static fragments, tile idx = 2*gate + s ----
    // A row m=c0 -> weight row 32*gate + 8*(c0>>2) + 4*s + (c0&3)
    // C row  m=4q+i -> weight row 32*gate + 8*q + 4*s + i
    bf16x8 AW[6], AX[6], AFC;
    f32x4  CBrz[4];   // r/z: full bias (bih+bhh) via the x-MFMA C operand
    f32x4  CBxn[2];   // n: bih via x-MFMA C
    f32x4  CBhn[2];   // n: bhh via h-MFMA C
    f32x4  CZ;
    CZ[0] = 0.f; CZ[1] = 0.f; CZ[2] = 0.f; CZ[3] = 0.f;
    #pragma unroll
    for (int gate = 0; gate < 3; ++gate) {
        const float gsc = (gate < 2) ? -L2E : 2.0f * L2E;
        #pragma unroll
        for (int s = 0; s < 2; ++s) {
            const int idx  = 2 * gate + s;
            const int arow = 32 * gate + 8 * (c0 >> 2) + 4 * s + (c0 & 3);
            const float* wrow = Whh + arow * 32 + q * 8;
            #pragma unroll
            for (int j = 0; j < 8; ++j) AW[idx][j] = (__bf16)(gsc * wrow[j]);
            #pragma unroll
            for (int j = 0; j < 8; ++j)
                AX[idx][j] = (q == 0 && j < 3) ? (__bf16)(gsc * Wih[arow * 3 + j])
                                               : (__bf16)0.0f;
            #pragma unroll
            for (int i = 0; i < 4; ++i) {
                const int crow = 32 * gate + 8 * q + 4 * s + i;
                if (gate < 2)  CBrz[idx][i] = gsc * (Bih[crow] + Bhh[crow]);
                else         { CBxn[s][i]   = gsc * Bih[crow];
                               CBhn[s][i]   = gsc * Bhh[crow]; }
            }
        }
    }
    // fc tile: A row 0 = fc_w over all 32 units (natural k order)
    #pragma unroll
    for (int j = 0; j < 8; ++j)
        AFC[j] = (c0 == 0) ? (__bf16)fc_w[dir * 32 + q * 8 + j] : (__bf16)0.0f;

    // ---- h state: this lane's 4 owned fp32 elements + full bf16 B fragment ----
    float hown[4] = {0.f, 0.f, 0.f, 0.f};   // lo: units 8q+i ; hi: units 8q+4+i
    bf16x8 Bh;
    #pragma unroll
    for (int j = 0; j < 8; ++j) Bh[j] = (__bf16)0.0f;

    // x pointer-walk: lane loads x[t][b0+bl][0..2] (cols duplicate mod 8)
    const int  t_first = dir ? (TT - 1) : 0;
    const long xstep   = dir ? -(long)(BB * 3) : (long)(BB * 3);
    const long ostep   = dir ? -(long)BB : (long)BB;
    const float* xp = x + (size_t)t_first * (BB * 3) + (size_t)(b0 + bl) * 3;
    float* chunk_ptr = outp + (size_t)t_first * BB + b0;   // out row of t=0

    float xa = xp[0], xb = xp[1], xc = xp[2];
    float fcb[8];

    for (int cch = 0; cch < TT / 8; ++cch) {
        #pragma unroll
        for (int s = 0; s < 8; ++s) {
            const int t = cch * 8 + s;

            // x B-fragment: rows k<3 only (AX zero elsewhere)
            bf16x8 Bx;
            Bx[0] = (__bf16)xa; Bx[1] = (__bf16)xb; Bx[2] = (__bf16)xc;
            Bx[3] = (__bf16)0.f; Bx[4] = (__bf16)0.f; Bx[5] = (__bf16)0.f;
            Bx[6] = (__bf16)0.f; Bx[7] = (__bf16)0.f;

            // prefetch next x (clamped on the final step)
            const float* xpn = (t < TT - 1) ? (xp + xstep) : xp;
            float nxa = xpn[0], nxb = xpn[1], nxc = xpn[2];
            xp = xpn;

            // r/z: x-MFMA (full bias in C) chains into h-MFMA C operand
            f32x4 D[6];
            #pragma unroll
            for (int g = 0; g < 4; ++g) {
                f32x4 Dx = __builtin_amdgcn_mfma_f32_16x16x32_bf16(AX[g], Bx, CBrz[g], 0, 0, 0);
                D[g]     = __builtin_amdgcn_mfma_f32_16x16x32_bf16(AW[g], Bh, Dx,      0, 0, 0);
            }
            // n: x and h parts separate (r multiplies only the h part)
            f32x4 Dxn[2];
            #pragma unroll
            for (int ss = 0; ss < 2; ++ss) {
                Dxn[ss]   = __builtin_amdgcn_mfma_f32_16x16x32_bf16(AX[4 + ss], Bx, CBxn[ss], 0, 0, 0);
                D[4 + ss] = __builtin_amdgcn_mfma_f32_16x16x32_bf16(AW[4 + ss], Bh, CBhn[ss], 0, 0, 0);
            }

            // trans-split: each lane-half computes only its own unit-half
            f32x4 Dr  = lo ? D[0]   : D[1];
            f32x4 Dz  = lo ? D[2]   : D[3];
            f32x4 Dnh = lo ? D[4]   : D[5];
            f32x4 Dnx = lo ? Dxn[0] : Dxn[1];
            #pragma unroll
            for (int i = 0; i < 4; ++i) {
                float r = frcp(1.0f + fexp2(Dr[i]));
                float z = frcp(1.0f + fexp2(Dz[i]));
                float e = fexp2(fmaf(r, Dnh[i], Dnx[i]));
                float n = fmaf(-2.0f, frcp(1.0f + e), 1.0f);
                hown[i] = fmaf(z, hown[i] - n, n);   // (1-z)*n + z*h
            }

            // pack own half, exchange with duplicate lane (lane^8), assemble Bh
            bf16x4 hv;
            #pragma unroll
            for (int i = 0; i < 4; ++i) hv[i] = (__bf16)hown[i];
            u32x2 own = __builtin_bit_cast(u32x2, hv);
            u32 sx = (u32)__shfl_xor((int)own.x, 8, 64);
            u32 sy = (u32)__shfl_xor((int)own.y, 8, 64);
            u32x4 asm4;
            asm4.x = lo ? own.x : sx;    // hA (units 8q+0..3)
            asm4.y = lo ? own.y : sy;
            asm4.z = lo ? sx : own.x;    // hB (units 8q+4..7)
            asm4.w = lo ? sy : own.y;
            Bh = __builtin_bit_cast(bf16x8, asm4);

            // fused FC on the NEW Bh (= h after update t) -> out row t
            f32x4 Dfc = __builtin_amdgcn_mfma_f32_16x16x32_bf16(AFC, Bh, CZ, 0, 0, 0);
            fcb[s] = Dfc[0];

            xa = nxa; xb = nxb; xc = nxc;
        }

        // flush 8 fc rows (rows 8c..8c+7); only lanes q==0, c0<8 store
        if (q == 0 && c0 < 8) {
            #pragma unroll
            for (int s = 0; s < 8; ++s) {
                float* op = chunk_ptr + s * ostep + c0;
                if (atomic_mode) atomicAdd(op, fcb[s]);
                else             *op = fcb[s];
            }
        }
        chunk_ptr += 8 * ostep;
    }
}

extern "C" void kernel_launch(void* const* d_in, const int* in_sizes, int n_in,
                              void* d_out, int out_size, void* d_ws, size_t ws_size,
                              hipStream_t stream) {
    const float* x      = (const float*)d_in[0];
    const float* w_ih_f = (const float*)d_in[1];
    const float* w_hh_f = (const float*)d_in[2];
    const float* b_ih_f = (const float*)d_in[3];
    const float* b_hh_f = (const float*)d_in[4];
    const float* w_ih_b = (const float*)d_in[5];
    const float* w_hh_b = (const float*)d_in[6];
    const float* b_ih_b = (const float*)d_in[7];
    const float* b_hh_b = (const float*)d_in[8];
    const float* fc_w   = (const float*)d_in[9];
    const float* fc_b   = (const float*)d_in[10];
    float* out = (float*)d_out;
    float* ws  = (float*)d_ws;

    const size_t need = (size_t)TT * BB * sizeof(float);
    dim3 grid(BB / 8, 2);   // 512 tiles x 2 dirs = 1024 single-wave blocks

    if (ws_size >= need) {
        // store path: fwd -> out, bwd -> ws, then combine (adds fc_b)
        gru_scan<<<grid, 64, 0, stream>>>(
            x, w_ih_f, w_hh_f, b_ih_f, b_hh_f,
            w_ih_b, w_hh_b, b_ih_b, b_hh_b, fc_w, out, ws, 0);
        gru_combine<<<(TT * BB / 4) / 256, 256, 0, stream>>>(out, ws, fc_b);
    } else {
        // atomic fallback: init out with fc_b, both dirs accumulate
        gru_init_out<<<(TT * BB / 4 + 255) / 256, 256, 0, stream>>>(out, fc_b);
        gru_scan<<<grid, 64, 0, stream>>>(
            x, w_ih_f, w_hh_f, b_ih_f, b_hh_f,
            w_ih_b, w_hh_b, b_ih_b, b_hh_b, fc_w, out, out, 1);
    }
}